// Round 10
// baseline (650.585 us; speedup 1.0000x reference)
//
#include <hip/hip_runtime.h>

// ---------------------------------------------------------------------------
// GraphTransformerWithPooling on MI355X (gfx950)
// R10: load-balanced gather. R9's node-centric gather wastes ~30% of wave
// cycles on degree divergence (wave time = max of 4 groups' degrees).
// Phase A now processes the tile's contiguous edge range in 8-edge chunks
// grabbed round-robin by 16-lane groups (perfect balance), accumulating in
// registers and flushing partials via LDS fp32 atomicAdd (~2 flushes/chunk).
// Phase B converts the fp32 LDS accumulator to bf16 A-frags (fused ReLU)
// and runs the 64xCOLS MFMA tile as before.
// 9 dispatches: prep, hist, scan_fuse, fill, gemm1, fused x4.
// ---------------------------------------------------------------------------

static inline int ceil_div(int a, int b) { return (a + b - 1) / b; }

typedef __attribute__((ext_vector_type(8))) short bf16x8;  // MFMA A/B frag
typedef __attribute__((ext_vector_type(4))) float f32x4;   // MFMA C/D frag

__device__ inline unsigned short f2bf(float f) {   // fp32 -> bf16 RNE
    unsigned u = __float_as_uint(f);
    return (unsigned short)((u + 0x7fffu + ((u >> 16) & 1u)) >> 16);
}

// ---------------- prep: zero cursor/stat, expand W1/W2/Wout into frags ------
// Frag layout t = ((ct*4+c)*64+lane)*8+j <-> k = c*32+(lane>>4)*8+j,
//   col = ct*16+(lane&15); a wave's 16B load of hi[] is the MFMA B fragment.

__device__ void wprep_dev(const float* __restrict__ W, unsigned short* __restrict__ hi,
                          int total, int C, int g0, int G) {
    for (int t = g0; t < total; t += G) {
        int j = t & 7;
        int lane = (t >> 3) & 63;
        int f = t >> 9;
        int c = f & 3, ct = f >> 2;
        int k = c * 32 + (lane >> 4) * 8 + j;
        int col = ct * 16 + (lane & 15);
        hi[t] = f2bf(W[(size_t)k * C + col]);
    }
}

__global__ __launch_bounds__(256) void prep_kernel(const float* __restrict__ W1,
                                                   const float* __restrict__ W2,
                                                   const float* __restrict__ Wout,
                                                   unsigned short* __restrict__ W1hi,
                                                   unsigned short* __restrict__ W2hi,
                                                   unsigned short* __restrict__ Wohi,
                                                   int* __restrict__ cursor,
                                                   unsigned* __restrict__ stat,
                                                   int N, int nChunks) {
    int g0 = blockIdx.x * 256 + threadIdx.x;
    int G = gridDim.x * 256;
    for (int i = g0; i < N; i += G) cursor[i] = 0;
    for (int i = g0; i < nChunks; i += G) stat[i] = 0;
    wprep_dev(W1, W1hi, 128 * 128, 128, g0, G);
    wprep_dev(W2, W2hi, 128 * 128, 128, g0, G);
    wprep_dev(Wout, Wohi, 128 * 64, 64, g0, G);
}

// ---------------- CSR build ----------------

__global__ __launch_bounds__(256) void hist_kernel(const int* __restrict__ dst,
                                                   int* __restrict__ deg, int E) {
    int e = blockIdx.x * 256 + threadIdx.x;
    if (e < E) atomicAdd(&deg[dst[e]], 1);
}

// Merged scan: publish chunk total (flag bit), spin-read predecessors
// (publishers never wait -> no deadlock). Writes rp, seeds fill cursor.
__global__ __launch_bounds__(256) void scan_fuse_kernel(const int* __restrict__ deg,
                                                        int* __restrict__ rp,
                                                        int* __restrict__ cursor,
                                                        unsigned* __restrict__ stat,
                                                        int N) {
    __shared__ int s[256];
    int c = blockIdx.x, tid = threadIdx.x;
    int i = c * 256 + tid;
    int v = (i < N) ? deg[i] : 0;
    s[tid] = v;
    __syncthreads();
    for (int off = 1; off < 256; off <<= 1) {
        int t = (tid >= off) ? s[tid - off] : 0;
        __syncthreads();
        s[tid] += t;
        __syncthreads();
    }
    int loc = s[tid] - v;
    int tot = s[255];
    __syncthreads();
    if (tid == 0) atomicExch(&stat[c], (unsigned)tot | 0x80000000u);

    unsigned mine = 0;
    if (tid < c) {
        unsigned u;
        do { u = atomicAdd(&stat[tid], 0u); } while (!(u & 0x80000000u));
        mine = u & 0x7fffffffu;
    }
    s[tid] = (int)mine;
    __syncthreads();
    for (int off = 128; off >= 1; off >>= 1) {
        if (tid < off) s[tid] += s[tid + off];
        __syncthreads();
    }
    int prefix = s[0];
    if (i <= N) {
        int val = loc + prefix;
        rp[i] = val;
        if (i < N) cursor[i] = val;
    }
}

__global__ __launch_bounds__(256) void fill_kernel(const int* __restrict__ src,
                                                   const int* __restrict__ dst,
                                                   int* __restrict__ cursor,
                                                   unsigned short* __restrict__ es, int E) {
    int e = blockIdx.x * 256 + threadIdx.x;
    if (e < E) {
        int p = atomicAdd(&cursor[dst[e]], 1);
        es[p] = (unsigned short)src[e];
    }
}

// ---------------- GEMM1: Y[n,128] = bf16(X_f32)[n,128] @ W1 + b1 -> bf16 ----
// 64 rows/block, 4 waves, no LDS, W frags streamed (L2-hot).

__global__ __launch_bounds__(256) void gemm1_kernel(const float* __restrict__ X,
                                                    const uint4* __restrict__ Whi,
                                                    const float* __restrict__ Bias,
                                                    unsigned short* __restrict__ Y, int n) {
    int tid = threadIdx.x;
    int wave = tid >> 6, lane = tid & 63;
    int lm = lane & 15, lq = lane >> 4;
    int r0 = blockIdx.x * 64;

    bf16x8 afr[4][4];
#pragma unroll
    for (int rt = 0; rt < 4; ++rt) {
        int ar = r0 + rt * 16 + lm;
        if (ar > n - 1) ar = n - 1;
#pragma unroll
        for (int c = 0; c < 4; ++c) {
            int k = c * 32 + lq * 8;
            const float* ap = X + (size_t)ar * 128 + k;
            float4 f0 = ((const float4*)ap)[0];
            float4 f1 = ((const float4*)ap)[1];
            bf16x8 v;
            v[0] = (short)f2bf(f0.x); v[1] = (short)f2bf(f0.y);
            v[2] = (short)f2bf(f0.z); v[3] = (short)f2bf(f0.w);
            v[4] = (short)f2bf(f1.x); v[5] = (short)f2bf(f1.y);
            v[6] = (short)f2bf(f1.z); v[7] = (short)f2bf(f1.w);
            afr[rt][c] = v;
        }
    }

    f32x4 acc[4][2];
#pragma unroll
    for (int rt = 0; rt < 4; ++rt)
#pragma unroll
        for (int t = 0; t < 2; ++t)
            acc[rt][t] = (f32x4){0.f, 0.f, 0.f, 0.f};

#pragma unroll
    for (int c = 0; c < 4; ++c) {
#pragma unroll
        for (int t = 0; t < 2; ++t) {
            int ct = wave * 2 + t;
            uint4 uh = Whi[(ct * 4 + c) * 64 + lane];
            bf16x8 wh = *(const bf16x8*)&uh;
#pragma unroll
            for (int rt = 0; rt < 4; ++rt)
                acc[rt][t] = __builtin_amdgcn_mfma_f32_16x16x32_bf16(afr[rt][c], wh, acc[rt][t], 0, 0, 0);
        }
    }

#pragma unroll
    for (int t = 0; t < 2; ++t) {
        int col = (wave * 2 + t) * 16 + lm;
        float bias = Bias[col];
#pragma unroll
        for (int rt = 0; rt < 4; ++rt) {
#pragma unroll
            for (int r = 0; r < 4; ++r) {
                int row = r0 + rt * 16 + lq * 4 + r;
                if (row < n)
                    Y[(size_t)row * 128 + col] = f2bf(acc[rt][t][r] + bias);
            }
        }
    }
}

// ---------------- Fused aggregate + GEMM (balanced edge-chunk gather) -------
// Block owns 64 nodes. Phase A: contiguous edge range split into 8-edge
// chunks; 16 lane-groups take chunks round-robin (perfect load balance).
// Row loads issued before the node binary-search (MLP); register partials
// flushed into fp32 LDS accumulator via atomicAdd (~2 flushes/chunk).
// Phase B: 4 waves, 64xCOLS MFMA tile; A-frags cvt'd from the fp32 LDS
// accumulator (fused ReLU), W frags streamed (L2-hot).

__device__ inline void acc_row8(float* a, uint4 v) {
    a[0] += __uint_as_float(v.x << 16);
    a[1] += __uint_as_float(v.x & 0xffff0000u);
    a[2] += __uint_as_float(v.y << 16);
    a[3] += __uint_as_float(v.y & 0xffff0000u);
    a[4] += __uint_as_float(v.z << 16);
    a[5] += __uint_as_float(v.z & 0xffff0000u);
    a[6] += __uint_as_float(v.w << 16);
    a[7] += __uint_as_float(v.w & 0xffff0000u);
}

template <int COLS, bool OUTF32>
__global__ __launch_bounds__(256) void fused_agg_gemm_kernel(const unsigned short* __restrict__ M,
                                                             const int* __restrict__ rp,
                                                             const unsigned short* __restrict__ es,
                                                             const uint4* __restrict__ Whi,
                                                             const float* __restrict__ Bias,
                                                             void* __restrict__ Yv,
                                                             int n, int do_relu) {
    constexpr int CT_W = COLS / 64;            // col-tiles per wave (128->2, 64->1)
    constexpr int SRF = 132;                   // fp32 acc row stride (16B-aligned)
    __shared__ float sAcc[64 * SRF];
    __shared__ int rpl[65];

    int tid = threadIdx.x;
    int r0 = blockIdx.x * 64;

    if (tid < 65) {
        int gi = r0 + tid;
        if (gi > n) gi = n;
        rpl[tid] = rp[gi];
    }
    for (int i = tid; i < 64 * SRF / 4; i += 256)
        ((float4*)sAcc)[i] = make_float4(0.f, 0.f, 0.f, 0.f);
    __syncthreads();

    // ---- Phase A: balanced edge-chunk gather ----
    {
        int g = tid >> 4, ln = tid & 15;
        int beg = rpl[0], end = rpl[64];
        int nc = (end - beg + 7) >> 3;
#pragma unroll 1
        for (int c = g; c < nc; c += 16) {
            int e0 = beg + (c << 3);
            int cnt = end - e0;
            if (cnt > 8) cnt = 8;

            int sidx[8];
#pragma unroll
            for (int j = 0; j < 8; ++j) sidx[j] = (j < cnt) ? (int)es[e0 + j] : 0;
            uint4 rows[8];
#pragma unroll
            for (int j = 0; j < 8; ++j)
                if (j < cnt) rows[j] = ((const uint4*)(M + (size_t)sidx[j] * 128))[ln];

            // largest nl with rpl[nl] <= e0 (range 64 -> 6 halvings)
            int lo = 0, hi = 64;
#pragma unroll
            for (int it = 0; it < 6; ++it) {
                int mid = (lo + hi) >> 1;
                if (rpl[mid] <= e0) lo = mid; else hi = mid;
            }
            int nl = lo;

            float acc[8] = {};
#pragma unroll
            for (int j = 0; j < 8; ++j) {
                if (j >= cnt) break;
                int e = e0 + j;
                if (e >= rpl[nl + 1]) {
#pragma unroll
                    for (int k = 0; k < 8; ++k)
                        atomicAdd(&sAcc[nl * SRF + ln * 8 + k], acc[k]);
#pragma unroll
                    for (int k = 0; k < 8; ++k) acc[k] = 0.f;
                    do { ++nl; } while (e >= rpl[nl + 1]);
                }
                acc_row8(acc, rows[j]);
            }
#pragma unroll
            for (int k = 0; k < 8; ++k)
                atomicAdd(&sAcc[nl * SRF + ln * 8 + k], acc[k]);
        }
    }
    __syncthreads();

    // ---- Phase B: 64xCOLS MFMA tile, A-frags cvt'd from fp32 LDS acc ----
    int wave = tid >> 6, lane = tid & 63;
    int lm = lane & 15, lq = lane >> 4;

    f32x4 acc[4][CT_W];
#pragma unroll
    for (int rt = 0; rt < 4; ++rt)
#pragma unroll
        for (int t = 0; t < CT_W; ++t)
            acc[rt][t] = (f32x4){0.f, 0.f, 0.f, 0.f};

#pragma unroll
    for (int c = 0; c < 4; ++c) {
        bf16x8 afr[4];
#pragma unroll
        for (int rt = 0; rt < 4; ++rt) {
            const float* ap = &sAcc[(rt * 16 + lm) * SRF + c * 32 + lq * 8];
            float4 a0 = ((const float4*)ap)[0];
            float4 a1 = ((const float4*)ap)[1];
            if (do_relu) {
                a0.x = fmaxf(a0.x, 0.f); a0.y = fmaxf(a0.y, 0.f);
                a0.z = fmaxf(a0.z, 0.f); a0.w = fmaxf(a0.w, 0.f);
                a1.x = fmaxf(a1.x, 0.f); a1.y = fmaxf(a1.y, 0.f);
                a1.z = fmaxf(a1.z, 0.f); a1.w = fmaxf(a1.w, 0.f);
            }
            bf16x8 v;
            v[0] = (short)f2bf(a0.x); v[1] = (short)f2bf(a0.y);
            v[2] = (short)f2bf(a0.z); v[3] = (short)f2bf(a0.w);
            v[4] = (short)f2bf(a1.x); v[5] = (short)f2bf(a1.y);
            v[6] = (short)f2bf(a1.z); v[7] = (short)f2bf(a1.w);
            afr[rt] = v;
        }
#pragma unroll
        for (int t = 0; t < CT_W; ++t) {
            int ct = wave * CT_W + t;
            uint4 uh = Whi[(ct * 4 + c) * 64 + lane];
            bf16x8 wh = *(const bf16x8*)&uh;
#pragma unroll
            for (int rt = 0; rt < 4; ++rt)
                acc[rt][t] = __builtin_amdgcn_mfma_f32_16x16x32_bf16(afr[rt], wh, acc[rt][t], 0, 0, 0);
        }
    }

    // C/D layout: col = lane&15, row = lq*4 + reg
#pragma unroll
    for (int t = 0; t < CT_W; ++t) {
        int col = (wave * CT_W + t) * 16 + lm;
        float bias = Bias[col];
#pragma unroll
        for (int rt = 0; rt < 4; ++rt) {
#pragma unroll
            for (int r = 0; r < 4; ++r) {
                int row = r0 + rt * 16 + lq * 4 + r;
                if (row < n) {
                    float v = acc[rt][t][r] + bias;
                    if (OUTF32)
                        ((float*)Yv)[(size_t)row * COLS + col] = v;
                    else
                        ((unsigned short*)Yv)[(size_t)row * COLS + col] = f2bf(v);
                }
            }
        }
    }
}

// ---------------- Launch ----------------

extern "C" void kernel_launch(void* const* d_in, const int* in_sizes, int n_in,
                              void* d_out, int out_size, void* d_ws, size_t ws_size,
                              hipStream_t stream) {
    const float* x    = (const float*)d_in[0];
    const int*   ei   = (const int*)d_in[1];
    const float* W1   = (const float*)d_in[2];
    const float* b1   = (const float*)d_in[3];
    const float* W2   = (const float*)d_in[4];
    const float* b2   = (const float*)d_in[5];
    const float* Wout = (const float*)d_in[6];
    const float* bout = (const float*)d_in[7];
    float*       out  = (float*)d_out;

    const int N = in_sizes[0] / 128;
    const int E = in_sizes[1] / 2;
    const int* src = ei;
    const int* dst = ei + E;

    char* ws = (char*)d_ws;
    auto take = [&](size_t bytes) {
        char* p = ws;
        ws += (bytes + 255) & ~(size_t)255;
        return p;
    };
    unsigned short* mA = (unsigned short*)take((size_t)N * 128 * 2);
    unsigned short* mB = (unsigned short*)take((size_t)N * 128 * 2);
    unsigned short* W1hi = (unsigned short*)take(128 * 128 * 2);
    unsigned short* W2hi = (unsigned short*)take(128 * 128 * 2);
    unsigned short* Wohi = (unsigned short*)take(128 * 64 * 2);
    int* rp      = (int*)take((size_t)(N + 1) * sizeof(int));
    int* cursor  = (int*)take((size_t)N * sizeof(int));
    unsigned short* es = (unsigned short*)take((size_t)E * sizeof(unsigned short));
    unsigned* stat = (unsigned*)take(4096);

    const int nChunks = ceil_div(N + 1, 256);   // 196 for N=50000 (<=256 required)
    const int tiles64 = ceil_div(N, 64);

    prep_kernel<<<256, 256, 0, stream>>>(W1, W2, Wout, W1hi, W2hi, Wohi,
                                         cursor, stat, N, nChunks);
    hist_kernel<<<ceil_div(E, 256), 256, 0, stream>>>(dst, cursor, E);
    scan_fuse_kernel<<<nChunks, 256, 0, stream>>>(cursor, rp, cursor, stat, N);
    fill_kernel<<<ceil_div(E, 256), 256, 0, stream>>>(src, dst, cursor, es, E);
    gemm1_kernel<<<tiles64, 256, 0, stream>>>(x, (const uint4*)W1hi, b1, mA, N);

    fused_agg_gemm_kernel<128, false><<<tiles64, 256, 0, stream>>>(
        mA, rp, es, (const uint4*)W1hi, b1, mB, N, 0);
    fused_agg_gemm_kernel<128, false><<<tiles64, 256, 0, stream>>>(
        mB, rp, es, (const uint4*)W2hi, b2, mA, N, 1);   // ReLU(agg) then *W2+b2
    fused_agg_gemm_kernel<128, false><<<tiles64, 256, 0, stream>>>(
        mA, rp, es, (const uint4*)W2hi, b2, mB, N, 0);
    fused_agg_gemm_kernel<64, true><<<tiles64, 256, 0, stream>>>(
        mB, rp, es, (const uint4*)Wohi, bout, out, N, 1); // ReLU(agg) then *Wout
}

// Round 11
// 288.079 us; speedup vs baseline: 2.2584x; 2.2584x over previous
//
#include <hip/hip_runtime.h>

// ---------------------------------------------------------------------------
// GraphTransformerWithPooling on MI355X (gfx950)
// R11: revert R10 (LDS-atomic balancing cost > divergence saved). R9 node-
// centric gather + static degree-ranked assignment instead: block ranks its
// 64 nodes by degree (LDS, 64x64 compares), slot q of group g takes rank
// q*16+g -> a wave's 4 lockstep groups get adjacent-rank (= nearly equal
// degree) nodes. No atomics, plain LDS stores, 17.4 KB LDS (8 blocks/CU).
// 9 dispatches: prep, hist, scan_fuse, fill, gemm1, fused x4.
// bf16 MFMA (16x16x32), single-rounded bf16 W, fp32 accumulation.
// ---------------------------------------------------------------------------

static inline int ceil_div(int a, int b) { return (a + b - 1) / b; }

typedef __attribute__((ext_vector_type(8))) short bf16x8;  // MFMA A/B frag
typedef __attribute__((ext_vector_type(4))) float f32x4;   // MFMA C/D frag

__device__ inline unsigned short f2bf(float f) {   // fp32 -> bf16 RNE
    unsigned u = __float_as_uint(f);
    return (unsigned short)((u + 0x7fffu + ((u >> 16) & 1u)) >> 16);
}

// ---------------- prep: zero cursor/stat, expand W1/W2/Wout into frags ------
// Frag layout t = ((ct*4+c)*64+lane)*8+j <-> k = c*32+(lane>>4)*8+j,
//   col = ct*16+(lane&15); a wave's 16B load of hi[] is the MFMA B fragment.

__device__ void wprep_dev(const float* __restrict__ W, unsigned short* __restrict__ hi,
                          int total, int C, int g0, int G) {
    for (int t = g0; t < total; t += G) {
        int j = t & 7;
        int lane = (t >> 3) & 63;
        int f = t >> 9;
        int c = f & 3, ct = f >> 2;
        int k = c * 32 + (lane >> 4) * 8 + j;
        int col = ct * 16 + (lane & 15);
        hi[t] = f2bf(W[(size_t)k * C + col]);
    }
}

__global__ __launch_bounds__(256) void prep_kernel(const float* __restrict__ W1,
                                                   const float* __restrict__ W2,
                                                   const float* __restrict__ Wout,
                                                   unsigned short* __restrict__ W1hi,
                                                   unsigned short* __restrict__ W2hi,
                                                   unsigned short* __restrict__ Wohi,
                                                   int* __restrict__ cursor,
                                                   unsigned* __restrict__ stat,
                                                   int N, int nChunks) {
    int g0 = blockIdx.x * 256 + threadIdx.x;
    int G = gridDim.x * 256;
    for (int i = g0; i < N; i += G) cursor[i] = 0;
    for (int i = g0; i < nChunks; i += G) stat[i] = 0;
    wprep_dev(W1, W1hi, 128 * 128, 128, g0, G);
    wprep_dev(W2, W2hi, 128 * 128, 128, g0, G);
    wprep_dev(Wout, Wohi, 128 * 64, 64, g0, G);
}

// ---------------- CSR build ----------------

__global__ __launch_bounds__(256) void hist_kernel(const int* __restrict__ dst,
                                                   int* __restrict__ deg, int E) {
    int e = blockIdx.x * 256 + threadIdx.x;
    if (e < E) atomicAdd(&deg[dst[e]], 1);
}

// Merged scan: publish chunk total (flag bit), spin-read predecessors
// (publishers never wait -> no deadlock). Writes rp, seeds fill cursor.
__global__ __launch_bounds__(256) void scan_fuse_kernel(const int* __restrict__ deg,
                                                        int* __restrict__ rp,
                                                        int* __restrict__ cursor,
                                                        unsigned* __restrict__ stat,
                                                        int N) {
    __shared__ int s[256];
    int c = blockIdx.x, tid = threadIdx.x;
    int i = c * 256 + tid;
    int v = (i < N) ? deg[i] : 0;
    s[tid] = v;
    __syncthreads();
    for (int off = 1; off < 256; off <<= 1) {
        int t = (tid >= off) ? s[tid - off] : 0;
        __syncthreads();
        s[tid] += t;
        __syncthreads();
    }
    int loc = s[tid] - v;
    int tot = s[255];
    __syncthreads();
    if (tid == 0) atomicExch(&stat[c], (unsigned)tot | 0x80000000u);

    unsigned mine = 0;
    if (tid < c) {
        unsigned u;
        do { u = atomicAdd(&stat[tid], 0u); } while (!(u & 0x80000000u));
        mine = u & 0x7fffffffu;
    }
    s[tid] = (int)mine;
    __syncthreads();
    for (int off = 128; off >= 1; off >>= 1) {
        if (tid < off) s[tid] += s[tid + off];
        __syncthreads();
    }
    int prefix = s[0];
    if (i <= N) {
        int val = loc + prefix;
        rp[i] = val;
        if (i < N) cursor[i] = val;
    }
}

__global__ __launch_bounds__(256) void fill_kernel(const int* __restrict__ src,
                                                   const int* __restrict__ dst,
                                                   int* __restrict__ cursor,
                                                   unsigned short* __restrict__ es, int E) {
    int e = blockIdx.x * 256 + threadIdx.x;
    if (e < E) {
        int p = atomicAdd(&cursor[dst[e]], 1);
        es[p] = (unsigned short)src[e];
    }
}

// ---------------- GEMM1: Y[n,128] = bf16(X_f32)[n,128] @ W1 + b1 -> bf16 ----
// 64 rows/block, 4 waves, no LDS, W frags streamed (L2-hot).

__global__ __launch_bounds__(256) void gemm1_kernel(const float* __restrict__ X,
                                                    const uint4* __restrict__ Whi,
                                                    const float* __restrict__ Bias,
                                                    unsigned short* __restrict__ Y, int n) {
    int tid = threadIdx.x;
    int wave = tid >> 6, lane = tid & 63;
    int lm = lane & 15, lq = lane >> 4;
    int r0 = blockIdx.x * 64;

    bf16x8 afr[4][4];
#pragma unroll
    for (int rt = 0; rt < 4; ++rt) {
        int ar = r0 + rt * 16 + lm;
        if (ar > n - 1) ar = n - 1;
#pragma unroll
        for (int c = 0; c < 4; ++c) {
            int k = c * 32 + lq * 8;
            const float* ap = X + (size_t)ar * 128 + k;
            float4 f0 = ((const float4*)ap)[0];
            float4 f1 = ((const float4*)ap)[1];
            bf16x8 v;
            v[0] = (short)f2bf(f0.x); v[1] = (short)f2bf(f0.y);
            v[2] = (short)f2bf(f0.z); v[3] = (short)f2bf(f0.w);
            v[4] = (short)f2bf(f1.x); v[5] = (short)f2bf(f1.y);
            v[6] = (short)f2bf(f1.z); v[7] = (short)f2bf(f1.w);
            afr[rt][c] = v;
        }
    }

    f32x4 acc[4][2];
#pragma unroll
    for (int rt = 0; rt < 4; ++rt)
#pragma unroll
        for (int t = 0; t < 2; ++t)
            acc[rt][t] = (f32x4){0.f, 0.f, 0.f, 0.f};

#pragma unroll
    for (int c = 0; c < 4; ++c) {
#pragma unroll
        for (int t = 0; t < 2; ++t) {
            int ct = wave * 2 + t;
            uint4 uh = Whi[(ct * 4 + c) * 64 + lane];
            bf16x8 wh = *(const bf16x8*)&uh;
#pragma unroll
            for (int rt = 0; rt < 4; ++rt)
                acc[rt][t] = __builtin_amdgcn_mfma_f32_16x16x32_bf16(afr[rt][c], wh, acc[rt][t], 0, 0, 0);
        }
    }

#pragma unroll
    for (int t = 0; t < 2; ++t) {
        int col = (wave * 2 + t) * 16 + lm;
        float bias = Bias[col];
#pragma unroll
        for (int rt = 0; rt < 4; ++rt) {
#pragma unroll
            for (int r = 0; r < 4; ++r) {
                int row = r0 + rt * 16 + lq * 4 + r;
                if (row < n)
                    Y[(size_t)row * 128 + col] = f2bf(acc[rt][t][r] + bias);
            }
        }
    }
}

// ---------------- Fused aggregate + GEMM (degree-ranked Phase A) ------------
// Block owns 64 nodes. Rank nodes by degree (64x64 compares in LDS); slot q
// of 16-lane group g processes rank q*16+g so a wave's 4 lockstep groups get
// adjacent-rank (nearly equal degree) nodes. Gather: bf16 rows, fp32 acc,
// optional ReLU, plain LDS stores (stride 136: 2-way aliasing = free).
// Phase B: 4 waves, 64xCOLS MFMA tile, A from LDS, W frags streamed (L2-hot).

__device__ inline void acc_row8(float* a, uint4 v) {
    a[0] += __uint_as_float(v.x << 16);
    a[1] += __uint_as_float(v.x & 0xffff0000u);
    a[2] += __uint_as_float(v.y << 16);
    a[3] += __uint_as_float(v.y & 0xffff0000u);
    a[4] += __uint_as_float(v.z << 16);
    a[5] += __uint_as_float(v.z & 0xffff0000u);
    a[6] += __uint_as_float(v.w << 16);
    a[7] += __uint_as_float(v.w & 0xffff0000u);
}

template <int COLS, bool OUTF32>
__global__ __launch_bounds__(256) void fused_agg_gemm_kernel(const unsigned short* __restrict__ M,
                                                             const int* __restrict__ rp,
                                                             const unsigned short* __restrict__ es,
                                                             const uint4* __restrict__ Whi,
                                                             const float* __restrict__ Bias,
                                                             void* __restrict__ Yv,
                                                             int n, int do_relu) {
    constexpr int CT_W = COLS / 64;            // col-tiles per wave (128->2, 64->1)
    constexpr int SR = 136;                    // LDS row stride in bf16
    __shared__ unsigned short Hl[64 * SR];
    __shared__ int rpl[65];
    __shared__ unsigned char perm[64];         // rank -> local node index

    int tid = threadIdx.x;
    int r0 = blockIdx.x * 64;

    if (tid < 65) {
        int gi = r0 + tid;
        if (gi > n) gi = n;
        rpl[tid] = rp[gi];
    }
    __syncthreads();

    // rank nodes by degree (descending; ties by index) — 64 threads, 64 cmp each
    if (tid < 64) {
        int di = rpl[tid + 1] - rpl[tid];
        int rank = 0;
        for (int j = 0; j < 64; ++j) {
            int dj = rpl[j + 1] - rpl[j];
            rank += (dj > di) || (dj == di && j < tid);
        }
        perm[rank] = (unsigned char)tid;
    }
    __syncthreads();

    // ---- Phase A: gather; slot q of group g handles rank q*16+g ----
    {
        int g = tid >> 4, ln = tid & 15;
#pragma unroll 1
        for (int q = 0; q < 4; ++q) {
            int nl = perm[q * 16 + g];
            int beg = rpl[nl], end = rpl[nl + 1];
            float acc[8] = {};
            int e = beg;
            for (; e + 8 <= end; e += 8) {
                int s0 = es[e],     s1 = es[e + 1], s2 = es[e + 2], s3 = es[e + 3];
                int s4 = es[e + 4], s5 = es[e + 5], s6 = es[e + 6], s7 = es[e + 7];
                uint4 v0 = ((const uint4*)(M + (size_t)s0 * 128))[ln];
                uint4 v1 = ((const uint4*)(M + (size_t)s1 * 128))[ln];
                uint4 v2 = ((const uint4*)(M + (size_t)s2 * 128))[ln];
                uint4 v3 = ((const uint4*)(M + (size_t)s3 * 128))[ln];
                uint4 v4 = ((const uint4*)(M + (size_t)s4 * 128))[ln];
                uint4 v5 = ((const uint4*)(M + (size_t)s5 * 128))[ln];
                uint4 v6 = ((const uint4*)(M + (size_t)s6 * 128))[ln];
                uint4 v7 = ((const uint4*)(M + (size_t)s7 * 128))[ln];
                acc_row8(acc, v0); acc_row8(acc, v1);
                acc_row8(acc, v2); acc_row8(acc, v3);
                acc_row8(acc, v4); acc_row8(acc, v5);
                acc_row8(acc, v6); acc_row8(acc, v7);
            }
            for (; e + 4 <= end; e += 4) {
                int s0 = es[e], s1 = es[e + 1], s2 = es[e + 2], s3 = es[e + 3];
                uint4 v0 = ((const uint4*)(M + (size_t)s0 * 128))[ln];
                uint4 v1 = ((const uint4*)(M + (size_t)s1 * 128))[ln];
                uint4 v2 = ((const uint4*)(M + (size_t)s2 * 128))[ln];
                uint4 v3 = ((const uint4*)(M + (size_t)s3 * 128))[ln];
                acc_row8(acc, v0); acc_row8(acc, v1);
                acc_row8(acc, v2); acc_row8(acc, v3);
            }
            for (; e < end; ++e) {
                uint4 v = ((const uint4*)(M + (size_t)es[e] * 128))[ln];
                acc_row8(acc, v);
            }
            if (do_relu) {
#pragma unroll
                for (int i = 0; i < 8; ++i) acc[i] = fmaxf(acc[i], 0.f);
            }
            uint4 o;
            o.x = (unsigned)f2bf(acc[0]) | ((unsigned)f2bf(acc[1]) << 16);
            o.y = (unsigned)f2bf(acc[2]) | ((unsigned)f2bf(acc[3]) << 16);
            o.z = (unsigned)f2bf(acc[4]) | ((unsigned)f2bf(acc[5]) << 16);
            o.w = (unsigned)f2bf(acc[6]) | ((unsigned)f2bf(acc[7]) << 16);
            *(uint4*)(&Hl[nl * SR + ln * 8]) = o;
        }
    }
    __syncthreads();

    // ---- Phase B: 64xCOLS MFMA tile, A from LDS ----
    int wave = tid >> 6, lane = tid & 63;
    int lm = lane & 15, lq = lane >> 4;

    f32x4 acc[4][CT_W];
#pragma unroll
    for (int rt = 0; rt < 4; ++rt)
#pragma unroll
        for (int t = 0; t < CT_W; ++t)
            acc[rt][t] = (f32x4){0.f, 0.f, 0.f, 0.f};

#pragma unroll
    for (int c = 0; c < 4; ++c) {
        bf16x8 afr[4];
#pragma unroll
        for (int rt = 0; rt < 4; ++rt)
            afr[rt] = *(const bf16x8*)(&Hl[(rt * 16 + lm) * SR + c * 32 + lq * 8]);
#pragma unroll
        for (int t = 0; t < CT_W; ++t) {
            int ct = wave * CT_W + t;
            uint4 uh = Whi[(ct * 4 + c) * 64 + lane];
            bf16x8 wh = *(const bf16x8*)&uh;
#pragma unroll
            for (int rt = 0; rt < 4; ++rt)
                acc[rt][t] = __builtin_amdgcn_mfma_f32_16x16x32_bf16(afr[rt], wh, acc[rt][t], 0, 0, 0);
        }
    }

    // C/D layout: col = lane&15, row = lq*4 + reg
#pragma unroll
    for (int t = 0; t < CT_W; ++t) {
        int col = (wave * CT_W + t) * 16 + lm;
        float bias = Bias[col];
#pragma unroll
        for (int rt = 0; rt < 4; ++rt) {
#pragma unroll
            for (int r = 0; r < 4; ++r) {
                int row = r0 + rt * 16 + lq * 4 + r;
                if (row < n) {
                    float v = acc[rt][t][r] + bias;
                    if (OUTF32)
                        ((float*)Yv)[(size_t)row * COLS + col] = v;
                    else
                        ((unsigned short*)Yv)[(size_t)row * COLS + col] = f2bf(v);
                }
            }
        }
    }
}

// ---------------- Launch ----------------

extern "C" void kernel_launch(void* const* d_in, const int* in_sizes, int n_in,
                              void* d_out, int out_size, void* d_ws, size_t ws_size,
                              hipStream_t stream) {
    const float* x    = (const float*)d_in[0];
    const int*   ei   = (const int*)d_in[1];
    const float* W1   = (const float*)d_in[2];
    const float* b1   = (const float*)d_in[3];
    const float* W2   = (const float*)d_in[4];
    const float* b2   = (const float*)d_in[5];
    const float* Wout = (const float*)d_in[6];
    const float* bout = (const float*)d_in[7];
    float*       out  = (float*)d_out;

    const int N = in_sizes[0] / 128;
    const int E = in_sizes[1] / 2;
    const int* src = ei;
    const int* dst = ei + E;

    char* ws = (char*)d_ws;
    auto take = [&](size_t bytes) {
        char* p = ws;
        ws += (bytes + 255) & ~(size_t)255;
        return p;
    };
    unsigned short* mA = (unsigned short*)take((size_t)N * 128 * 2);
    unsigned short* mB = (unsigned short*)take((size_t)N * 128 * 2);
    unsigned short* W1hi = (unsigned short*)take(128 * 128 * 2);
    unsigned short* W2hi = (unsigned short*)take(128 * 128 * 2);
    unsigned short* Wohi = (unsigned short*)take(128 * 64 * 2);
    int* rp      = (int*)take((size_t)(N + 1) * sizeof(int));
    int* cursor  = (int*)take((size_t)N * sizeof(int));
    unsigned short* es = (unsigned short*)take((size_t)E * sizeof(unsigned short));
    unsigned* stat = (unsigned*)take(4096);

    const int nChunks = ceil_div(N + 1, 256);   // 196 for N=50000 (<=256 required)
    const int tiles64 = ceil_div(N, 64);

    prep_kernel<<<256, 256, 0, stream>>>(W1, W2, Wout, W1hi, W2hi, Wohi,
                                         cursor, stat, N, nChunks);
    hist_kernel<<<ceil_div(E, 256), 256, 0, stream>>>(dst, cursor, E);
    scan_fuse_kernel<<<nChunks, 256, 0, stream>>>(cursor, rp, cursor, stat, N);
    fill_kernel<<<ceil_div(E, 256), 256, 0, stream>>>(src, dst, cursor, es, E);
    gemm1_kernel<<<tiles64, 256, 0, stream>>>(x, (const uint4*)W1hi, b1, mA, N);

    fused_agg_gemm_kernel<128, false><<<tiles64, 256, 0, stream>>>(
        mA, rp, es, (const uint4*)W1hi, b1, mB, N, 0);
    fused_agg_gemm_kernel<128, false><<<tiles64, 256, 0, stream>>>(
        mB, rp, es, (const uint4*)W2hi, b2, mA, N, 1);   // ReLU(agg) then *W2+b2
    fused_agg_gemm_kernel<128, false><<<tiles64, 256, 0, stream>>>(
        mA, rp, es, (const uint4*)W2hi, b2, mB, N, 0);
    fused_agg_gemm_kernel<64, true><<<tiles64, 256, 0, stream>>>(
        mB, rp, es, (const uint4*)Wohi, bout, out, N, 1); // ReLU(agg) then *Wout
}